// Round 1
// baseline (609.990 us; speedup 1.0000x reference)
//
#include <hip/hip_runtime.h>

// Per row (64 floats of exact {0,1}):
//   e     = bits x[1..11], x[1] = bit10 (MSB) ... x[11] = bit0
//   d     = (e - 1023) & 2047
//   mant6 = bits x[12..17], x[12] = bit5 (MSB) ... x[17] = bit0
//   low6  = (d <= 5) ? (((0x40 | mant6) << d) >> 6) & 63 : 0
//   out[j] = bit (5-j) of low6   (MSB first), j = 0..5
//
// V2: cooperative LDS staging. The old kernel issued 5 loads/thread, each
// fully lane-divergent (256-B stride -> 64 line-requests per instruction,
// 320 per wave). Here a block of 256 threads loads the 5*256 needed float4
// chunks in chunk-index order (adjacent lanes -> adjacent addresses, each
// cache line requested exactly once), and the 6-KB output block is written
// back fully coalesced as float4.

#define BLOCK 256
#define SLOTS 6  // float4 slots per row in LDS; 5 used, 6 breaks the 8-way
                 // bank alias that a 20-word stride would have on readback.

__global__ __launch_bounds__(BLOCK) void extract_low6_kernel(
    const float* __restrict__ x, float* __restrict__ out, int nrows) {
    __shared__ float4 stage[BLOCK * SLOTS];  // 24 KB input stage
    __shared__ float4 ostage4[BLOCK * 6 / 4];  // 6 KB output stage
    float* ostage = (float*)ostage4;

    const int t = threadIdx.x;
    const long long row0 = (long long)blockIdx.x * BLOCK;

    // ---- Coalesced staging: chunk g (0..1279) -> row g/5, c = g%5.
    // Global addr of chunk = (row0+row)*256B + c*16B. Consecutive lanes read
    // consecutive chunks: bytes 0..79 of a row back-to-back, then the next
    // row. ~13 lines per instruction instead of 64.
#pragma unroll
    for (int k = 0; k < 5; ++k) {
        int g = k * BLOCK + t;
        int row = g / 5;          // mul-shift, cheap
        int c = g - row * 5;
        if (row0 + row < nrows) {
            stage[row * SLOTS + c] =
                *(const float4*)(x + (((size_t)(row0 + row)) << 6) + (c << 2));
        }
    }
    __syncthreads();

    const bool valid = (row0 + t) < (long long)nrows;
    int low6 = 0;
    if (valid) {
        float4 f0 = stage[t * SLOTS + 0];  // cols 0..3   (col 0 = sign, unused)
        float4 f1 = stage[t * SLOTS + 1];  // cols 4..7
        float4 f2 = stage[t * SLOTS + 2];  // cols 8..11
        float4 f3 = stage[t * SLOTS + 3];  // cols 12..15
        float4 f4 = stage[t * SLOTS + 4];  // cols 16..19 (only .x,.y used)

        int e = 0;
        e |= (int)(f0.y != 0.f) << 10;  // x1
        e |= (int)(f0.z != 0.f) << 9;   // x2
        e |= (int)(f0.w != 0.f) << 8;   // x3
        e |= (int)(f1.x != 0.f) << 7;   // x4
        e |= (int)(f1.y != 0.f) << 6;   // x5
        e |= (int)(f1.z != 0.f) << 5;   // x6
        e |= (int)(f1.w != 0.f) << 4;   // x7
        e |= (int)(f2.x != 0.f) << 3;   // x8
        e |= (int)(f2.y != 0.f) << 2;   // x9
        e |= (int)(f2.z != 0.f) << 1;   // x10
        e |= (int)(f2.w != 0.f);        // x11

        int mant = 0;
        mant |= (int)(f3.x != 0.f) << 5;  // x12 (mantissa MSB)
        mant |= (int)(f3.y != 0.f) << 4;  // x13
        mant |= (int)(f3.z != 0.f) << 3;  // x14
        mant |= (int)(f3.w != 0.f) << 2;  // x15
        mant |= (int)(f4.x != 0.f) << 1;  // x16
        mant |= (int)(f4.y != 0.f);       // x17

        unsigned d = (unsigned)(e - 1023) & 2047u;
        low6 = (d <= 5u) ? (((0x40 | mant) << d) >> 6) & 63 : 0;

        // Stage the 6 output floats (stride 6 words -> only 2-way bank alias,
        // which is free on CDNA4).
        ostage[t * 6 + 0] = (float)((low6 >> 5) & 1);
        ostage[t * 6 + 1] = (float)((low6 >> 4) & 1);
        ostage[t * 6 + 2] = (float)((low6 >> 3) & 1);
        ostage[t * 6 + 3] = (float)((low6 >> 2) & 1);
        ostage[t * 6 + 4] = (float)((low6 >> 1) & 1);
        ostage[t * 6 + 5] = (float)(low6 & 1);
    }
    __syncthreads();

    const long long rem = (long long)nrows - row0;
    if (rem >= BLOCK) {
        // Full block: 256 rows * 24 B = 1536 floats = 384 float4, fully
        // coalesced store.
        float4* o4 = (float4*)(out + (size_t)row0 * 6);
        const float4* s4 = (const float4*)ostage4;
#pragma unroll
        for (int base = 0; base < 384; base += BLOCK) {
            int idx = base + t;
            if (idx < 384) o4[idx] = s4[idx];
        }
    } else if (valid) {
        // Tail block: fall back to per-row stores.
        float2* o = (float2*)(out + (size_t)(row0 + t) * 6);
        o[0] = make_float2((float)((low6 >> 5) & 1), (float)((low6 >> 4) & 1));
        o[1] = make_float2((float)((low6 >> 3) & 1), (float)((low6 >> 2) & 1));
        o[2] = make_float2((float)((low6 >> 1) & 1), (float)(low6 & 1));
    }
}

extern "C" void kernel_launch(void* const* d_in, const int* in_sizes, int n_in,
                              void* d_out, int out_size, void* d_ws, size_t ws_size,
                              hipStream_t stream) {
    const float* x = (const float*)d_in[0];
    float* out = (float*)d_out;
    int nrows = in_sizes[0] / 64;  // 2,000,000
    int grid = (nrows + BLOCK - 1) / BLOCK;
    extract_low6_kernel<<<grid, BLOCK, 0, stream>>>(x, out, nrows);
}